// Round 4
// baseline (38.280 us; speedup 1.0000x reference)
//
#include <hip/hip_runtime.h>
#include <hip/hip_bf16.h>

#define B_  32
#define N_  128
#define AH_ 512
#define AW_ 512

// ---------------------------------------------------------------------------
// One block = ONE wave (64 threads) handling TWO consecutive rows of one
// image. Box geometry (scale, floors, edge weights, validity) is computed
// ONCE per block into registers (2 boxes/lane); per row only the coverage
// test + ballot-compaction + span rasterize + BCE run.
// Single-wave blocks: no inter-wave lockstep; __syncthreads compiles to a
// near-free 1-wave barrier that just orders LDS ops.
// ---------------------------------------------------------------------------
__global__ __launch_bounds__(64) void row_bce_kernel(
    const float* __restrict__ att,
    const float* __restrict__ bboxs,
    const int*   __restrict__ img_h_p,
    const int*   __restrict__ img_w_p,
    float*       __restrict__ block_sums)
{
    const int lane = threadIdx.x;            // 0..63
    const int b    = blockIdx.x >> 8;        // 256 row-pairs per image
    const int y0   = (blockIdx.x & 255) << 1;

    __shared__ int2   s_xr[N_];              // {x1, x2}
    __shared__ float4 s_f[N_];               // {row, row*x1m, row*x2m, x2m}
    __shared__ float  s_mask[AW_];

    const float fw  = (float)(*img_w_p);
    const float fh  = (float)(*img_h_p);
    const float sxs = (float)AW_ / fw;
    const float sys = (float)AH_ / fh;

    // ---- box geometry, once per block (boxes lane and lane+64) ----
    bool  valid[2];
    int   gx1[2], gx2[2], gy1[2], gy2[2];
    float gx1m[2], gx2m[2], gy1m[2], gy2m[2];
    #pragma unroll
    for (int k = 0; k < 2; ++k) {
        const int n = lane + 64 * k;
        const float* bp = bboxs + ((size_t)b * N_ + n) * 5;
        const float c0 = bp[0], c1 = bp[1], c2 = bp[2], c3 = bp[3], lab = bp[4];
        valid[k] = (lab != -1.0f) && (c0 <= fw) && (c1 <= fh)
                                  && (c2 <= fw) && (c3 <= fh);
        const float bx1 = c0 * sxs, by1 = c1 * sys;
        const float bx2 = c2 * sxs, by2 = c3 * sys;
        const float fx1 = floorf(bx1), fy1 = floorf(by1);
        gx1m[k] = fx1 + 1.0f - bx1;
        gy1m[k] = fy1 + 1.0f - by1;
        gx2m[k] = bx2 - floorf(bx2);
        gy2m[k] = by2 - floorf(by2);
        gx1[k] = (int)fmaxf(fx1, 0.0f);
        gy1[k] = (int)fmaxf(fy1, 0.0f);
        gx2[k] = (int)fminf(ceilf(bx2) + 1.0f, (float)AW_);
        gy2[k] = (int)fminf(ceilf(by2) + 1.0f, (float)AH_);
    }

    const float4* p4base = (const float4*)(att + ((size_t)b * AH_ + y0) * AW_);
    float4* mrow4 = (float4*)s_mask;
    const unsigned long long ltm = (1ull << lane) - 1ull;
    float acc = 0.0f;

    for (int r = 0; r < 2; ++r) {
        const int y = y0 + r;

        // ---- per-row coverage + compaction ----
        bool   act[2];
        float4 f[2];
        #pragma unroll
        for (int k = 0; k < 2; ++k) {
            act[k] = valid[k] && (y >= gy1[k]) && (y < gy2[k]);
            const float row = ((y == gy1[k])     ? gy1m[k] : 1.0f)
                            * ((y == gy2[k] - 1) ? gy2m[k] : 1.0f);
            f[k] = make_float4(row, row * gx1m[k], row * gx2m[k], gx2m[k]);
        }
        const unsigned long long bal0 = __ballot(act[0]);
        const unsigned long long bal1 = __ballot(act[1]);
        const int c0n = __popcll(bal0);
        const int cnt = c0n + __popcll(bal1);
        if (act[0]) {
            const int slot = __popcll(bal0 & ltm);
            s_xr[slot] = make_int2(gx1[0], gx2[0]);
            s_f[slot]  = f[0];
        }
        if (act[1]) {
            const int slot = c0n + __popcll(bal1 & ltm);
            s_xr[slot] = make_int2(gx1[1], gx2[1]);
            s_f[slot]  = f[1];
        }
        __syncthreads();   // 1-wave: orders compaction writes before reads

        if (cnt > 0) {
            // ---- mask init + sequential span rasterize (last-wins) ----
            const float4 z = make_float4(0.f, 0.f, 0.f, 0.f);
            mrow4[lane]      = z;
            mrow4[lane + 64] = z;
            for (int i = 0; i < cnt; ++i) {
                const int2   e = s_xr[i];
                const float4 g = s_f[i];
                for (int x = e.x + lane; x < e.y; x += 64) s_mask[x] = g.x;
                if (lane == 0 && e.x < e.y)
                    s_mask[e.x] = (e.x == e.y - 1) ? g.y * g.w : g.y;
                if (lane == 1 && e.y - 1 > e.x)
                    s_mask[e.y - 1] = g.z;
            }
            __syncthreads();   // orders rasterize writes before BCE reads
        }

        // ---- BCE sweep: 2 chunks of 256 px (float4/lane) ----
        #pragma unroll
        for (int h = 0; h < 2; ++h) {
            const float4 p = p4base[r * 128 + lane + 64 * h];
            float4 m = make_float4(0.f, 0.f, 0.f, 0.f);
            if (cnt > 0) m = mrow4[lane + 64 * h];
            const float pv[4] = {p.x, p.y, p.z, p.w};
            const float mv[4] = {m.x, m.y, m.z, m.w};
            const bool nz = (m.x != 0.f) | (m.y != 0.f) | (m.z != 0.f) | (m.w != 0.f);
            if (__any(nz)) {
                #pragma unroll
                for (int j = 0; j < 4; ++j) {
                    const float lp = fmaxf(__logf(pv[j]),        -100.0f);
                    const float l1 = fmaxf(__logf(1.0f - pv[j]), -100.0f);
                    acc += l1 + mv[j] * (lp - l1);
                }
            } else {
                #pragma unroll
                for (int j = 0; j < 4; ++j)
                    acc += fmaxf(__logf(1.0f - pv[j]), -100.0f);
            }
        }
        __syncthreads();   // protect LDS reuse across rows
    }

    // ---- wave reduction -> per-block partial ----
    #pragma unroll
    for (int off = 32; off; off >>= 1) acc += __shfl_down(acc, off, 64);
    if (lane == 0) block_sums[blockIdx.x] = acc;
}

// ---------------------------------------------------------------------------
// Fused tail: per-image reduce of 256 block partials + any_valid gate +
// batch mean. One block, 1024 threads (32 workers per image).
// ---------------------------------------------------------------------------
__global__ __launch_bounds__(1024) void final_kernel(
    const float* __restrict__ bboxs,
    const int*   __restrict__ img_h_p,
    const int*   __restrict__ img_w_p,
    const float* __restrict__ block_sums,
    float*       __restrict__ out)
{
    const int t = threadIdx.x;
    const int b = t >> 5;        // image 0..31
    const int j = t & 31;        // worker within image

    __shared__ float s_sum[1024];
    __shared__ int   s_any[1024];
    __shared__ float s_loss[B_];

    float s = 0.0f;
    #pragma unroll
    for (int k = 0; k < 8; ++k) s += block_sums[b * 256 + j + 32 * k];
    s_sum[t] = s;

    const float fw = (float)(*img_w_p);
    const float fh = (float)(*img_h_p);
    int av = 0;
    const float* bp = bboxs + (size_t)b * N_ * 5;
    #pragma unroll
    for (int n = j * 4; n < j * 4 + 4; ++n) {
        const float c0 = bp[n * 5 + 0];
        const float c1 = bp[n * 5 + 1];
        const float c2 = bp[n * 5 + 2];
        const float c3 = bp[n * 5 + 3];
        const float lab = bp[n * 5 + 4];
        av |= ((lab != -1.0f) && (c0 <= fw) && (c1 <= fh)
                              && (c2 <= fw) && (c3 <= fh)) ? 1 : 0;
    }
    s_any[t] = av;
    __syncthreads();

    if (j == 0) {
        float sum = 0.0f;
        int anyv = 0;
        for (int k = 0; k < 32; ++k) {
            sum  += s_sum[b * 32 + k];
            anyv |= s_any[b * 32 + k];
        }
        s_loss[b] = anyv ? (-sum * (1.0f / (float)(AH_ * AW_))) : 0.0f;
    }
    __syncthreads();

    if (t == 0) {
        float total = 0.0f;
        for (int k = 0; k < B_; ++k) total += s_loss[k];
        out[0] = total * (1.0f / (float)B_);
    }
}

extern "C" void kernel_launch(void* const* d_in, const int* in_sizes, int n_in,
                              void* d_out, int out_size, void* d_ws, size_t ws_size,
                              hipStream_t stream)
{
    const float* att   = (const float*)d_in[0];   // (32,1,512,512) f32
    const float* bboxs = (const float*)d_in[1];   // (32,128,5) f32
    const int*   img_h = (const int*)d_in[2];     // scalar
    const int*   img_w = (const int*)d_in[3];     // scalar
    float* out = (float*)d_out;
    float* block_sums = (float*)d_ws;             // 8192 floats (32 KB)

    row_bce_kernel<<<B_ * AH_ / 2, 64, 0, stream>>>(att, bboxs, img_h, img_w, block_sums);
    final_kernel<<<1, 1024, 0, stream>>>(bboxs, img_h, img_w, block_sums, out);
}